// Round 12
// baseline (244.873 us; speedup 1.0000x reference)
//
#include <hip/hip_runtime.h>
#include <stdint.h>

typedef signed char i8;
typedef __attribute__((ext_vector_type(4))) float f32x4;
typedef __attribute__((ext_vector_type(4))) int i32x4;

#define XSCALE 32.0f
#define INV_XSCALE (1.0f / 32.0f)

// ---------------- conversion kernels ----------------

__device__ __forceinline__ int q8(float f) {
  float s = rintf(f * XSCALE);
  s = fminf(fmaxf(s, -127.0f), 127.0f);
  return ((int)s) & 0xff;
}

// x fp32 -> i8 (scale 32), 16 elems/thread
__global__ __launch_bounds__(256) void cvt_x_kernel(const float* __restrict__ x,
                                                    i32x4* __restrict__ o, int n16) {
  int i = blockIdx.x * blockDim.x + threadIdx.x;
  int stride = gridDim.x * blockDim.x;
  for (; i < n16; i += stride) {
    const f32x4* p = (const f32x4*)x + (size_t)i * 4;
    f32x4 v0 = p[0], v1 = p[1], v2 = p[2], v3 = p[3];
    i32x4 r;
    r[0] = q8(v0[0]) | (q8(v0[1]) << 8) | (q8(v0[2]) << 16) | (q8(v0[3]) << 24);
    r[1] = q8(v1[0]) | (q8(v1[1]) << 8) | (q8(v1[2]) << 16) | (q8(v1[3]) << 24);
    r[2] = q8(v2[0]) | (q8(v2[1]) << 8) | (q8(v2[2]) << 16) | (q8(v2[3]) << 24);
    r[3] = q8(v3[0]) | (q8(v3[1]) << 8) | (q8(v3[2]) << 16) | (q8(v3[3]) << 24);
    o[i] = r;
  }
}

__device__ __forceinline__ int sg8(float f) {
  return (f > 0.0f ? 1 : (f < 0.0f ? -1 : 0)) & 0xff;
}

// w fp32 -> sign i8 (+1/-1/0), 16 elems/thread
__global__ __launch_bounds__(256) void cvt_w_kernel(const float* __restrict__ w,
                                                    i32x4* __restrict__ o, int n16) {
  int i = blockIdx.x * blockDim.x + threadIdx.x;
  int stride = gridDim.x * blockDim.x;
  for (; i < n16; i += stride) {
    const f32x4* p = (const f32x4*)w + (size_t)i * 4;
    f32x4 v0 = p[0], v1 = p[1], v2 = p[2], v3 = p[3];
    i32x4 r;
    r[0] = sg8(v0[0]) | (sg8(v0[1]) << 8) | (sg8(v0[2]) << 16) | (sg8(v0[3]) << 24);
    r[1] = sg8(v1[0]) | (sg8(v1[1]) << 8) | (sg8(v1[2]) << 16) | (sg8(v1[3]) << 24);
    r[2] = sg8(v2[0]) | (sg8(v2[1]) << 8) | (sg8(v2[2]) << 16) | (sg8(v2[3]) << 24);
    r[3] = sg8(v3[0]) | (sg8(v3[1]) << 8) | (sg8(v3[2]) << 16) | (sg8(v3[3]) << 24);
    o[i] = r;
  }
}

// ---------------- 128x64 i8 GEMM, SINGLE-WAVE blocks, ZERO barriers -------
// r25: the convoy is barrier-group-induced (13 variants: time = LDS + MFMA
// + sync ADDITIVE within any one barrier group, regardless of schedule;
// only r20's independent groups moved, +7%). Push the mechanism to group
// size 1: block = 1 wave, tile 128x64, acc 128. No s_barrier anywhere --
// global_load_lds visibility to the issuing wave is pure vmcnt; LDS is
// block-private; zero cross-wave communication (race-free by construction).
// LDS 3 x (A 8KB + B 4KB) = 36KB -> 4 independent free-running waves/CU
// (1/SIMD -> register budget ~512: frag dbuf 96 + acc 128 fits easily).
// Per tile: stage S(t+2) (12 vmem) -> VMCNT12 (retire S(t+1), 1-tile
// lead) -> issue frags(t+1) (12 ds_read) -> WAITL(12) (retires frags(t),
// drained under last tile's MFMA) -> 32 MFMA. Reads always drain under
// MFMA; 4 desynced streams keep port + all 4 matrix pipes fed.
// XCD chunking tn-fast: each XCD chunk = 8 A-panels x 64 tn -> A L2-hot;
// B re-reads come from L3 (not HBM).

__device__ __forceinline__ void load_lds16(const void* g, void* l) {
  __builtin_amdgcn_global_load_lds(
      (const __attribute__((address_space(1))) void*)g,
      (__attribute__((address_space(3))) void*)l,
      16, 0, 0);
}

// stage one 1KB unit (16 rows x 64 cols i8) by one wave; u = unit index.
// Same 16B-granule involution as the read side: key = (row>>1)&3.
__device__ __forceinline__ void stage_u1(const i8* __restrict__ Gp, int K, int k0,
                                         i8* __restrict__ Tlds, int u, int lane) {
  const int base = u * 1024;                      // physical byte base
  const int PA = base + lane * 16;                // this lane's physical bytes
  const int L = PA ^ (((PA >> 7) & 3) << 4);      // logical bytes (involution)
  const int r = L >> 6;                           // tile row (64 i8 per row)
  const int c = L & 63;                           // tile col (16-aligned)
  load_lds16(Gp + (size_t)r * K + k0 + c, Tlds + base);
}

#define SGB __builtin_amdgcn_sched_barrier(0)
#define WAITL12 asm volatile("s_waitcnt lgkmcnt(12)" ::: "memory")
#define WAITL0 asm volatile("s_waitcnt lgkmcnt(0)" ::: "memory")
#define VMCNT12 asm volatile("s_waitcnt vmcnt(12)" ::: "memory")
#define VMCNT0 asm volatile("s_waitcnt vmcnt(0)" ::: "memory")

// Buffer layout per 12KB buf: A [128][64] at +0, B [64][64] at +8192.
#define STAGE12(PS, KOFF)                                                       \
  {                                                                             \
    stage_u1(GA, K, (KOFF), (PS), 0, lane);                                     \
    stage_u1(GA, K, (KOFF), (PS), 1, lane);                                     \
    stage_u1(GA, K, (KOFF), (PS), 2, lane);                                     \
    stage_u1(GA, K, (KOFF), (PS), 3, lane);                                     \
    stage_u1(GA, K, (KOFF), (PS), 4, lane);                                     \
    stage_u1(GA, K, (KOFF), (PS), 5, lane);                                     \
    stage_u1(GA, K, (KOFF), (PS), 6, lane);                                     \
    stage_u1(GA, K, (KOFF), (PS), 7, lane);                                     \
    stage_u1(GB, K, (KOFF), (PS) + 8192, 0, lane);                              \
    stage_u1(GB, K, (KOFF), (PS) + 8192, 1, lane);                              \
    stage_u1(GB, K, (KOFF), (PS) + 8192, 2, lane);                              \
    stage_u1(GB, K, (KOFF), (PS) + 8192, 3, lane);                              \
  }

#define READ_FRAGS(PTR, AF, BF)                                                 \
  _Pragma("unroll") for (int mi = 0; mi < 8; ++mi)                              \
    AF[mi] = *(const i32x4*)((PTR) + abase + mi * 1024);                        \
  _Pragma("unroll") for (int ni = 0; ni < 4; ++ni)                              \
    BF[ni] = *(const i32x4*)((PTR) + 8192 + bbase + ni * 1024);

#define MFMA32(AF, BF)                                                          \
  __builtin_amdgcn_s_setprio(1);                                                \
  _Pragma("unroll") for (int mi = 0; mi < 8; ++mi)                              \
  _Pragma("unroll") for (int ni = 0; ni < 4; ++ni)                              \
    acc[mi][ni] = __builtin_amdgcn_mfma_i32_16x16x64_i8(                        \
        AF[mi], BF[ni], acc[mi][ni], 0, 0, 0);                                  \
  __builtin_amdgcn_s_setprio(0);

// PR = buf[t%3] (current frags' source, already in AFc/BFc registers),
// PRN = buf[(t+1)%3] (read next frags), PS = buf[(t+2)%3] (stage t+2).
// vm ledger entering tile t: {S(t+1): 12}. lgkm entering: {frags(t): 12}.
#define DO_TILE(t, PR, PRN, PS, AFc, BFc, AFn, BFn)                             \
  if ((t) < NT) {                                                               \
    if ((t) + 2 < NT) {                                                         \
      STAGE12(PS, ((t) + 2) * 64);               /* vm: 24 */                   \
      VMCNT12;                                   /* retire S(t+1) */            \
    } else if ((t) + 1 < NT) { VMCNT0; }         /* tail: S(t+1) only */        \
    if ((t) + 1 < NT) {                                                         \
      READ_FRAGS(PRN, AFn, BFn);                 /* lgkm: 24 */                 \
      WAITL12; SGB;                              /* retires frags(t) */         \
    } else { WAITL0; SGB; }                                                     \
    MFMA32(AFc, BFc);                                                           \
    SGB;                                                                        \
  }

__global__ __launch_bounds__(64, 1) void bingemm1w_kernel(
    const i8* __restrict__ A,      // [M][K] i8 (x * 32)
    const i8* __restrict__ B,      // [N][K] i8 sign
    const float* __restrict__ alpha,
    const float* __restrict__ bias,
    float* __restrict__ C,         // [M][N] fp32
    int M, int N, int K) {
  __shared__ i8 SM[3][12288];      // 3 x (A 8KB + B 4KB) = 36 KB

  const int lane = threadIdx.x & 63;
  const int l15 = lane & 15;

  // XCD-aware swizzle (grid divisible by 8 -> simple bijection).
  // tn-fast inside each XCD chunk: consecutive wgid share the A panel.
  const int nwg = gridDim.x;
  const int wg = blockIdx.x;
  const int wgid = ((nwg & 7) == 0) ? ((wg & 7) * (nwg >> 3) + (wg >> 3)) : wg;

  const int nbn = N / 64;
  const int tm = wgid / nbn;
  const int tn = wgid % nbn;

  const i8* GA = A + (size_t)tm * 128 * K;
  const i8* GB = B + (size_t)tn * 64 * K;

  // swizzled ds_read byte offsets (row stride 64B, granule 16B):
  // phys k-part = (kq ^ ((row>>1)&3))<<4, (row>>1)&3 == (l15>>1)&3
  const int kq = lane >> 4;                 // 0..3
  const int kph = ((kq ^ ((l15 >> 1) & 3)) << 4);
  const int abase = l15 * 64 + kph;         // + mi*1024 (16 rows each)
  const int bbase = l15 * 64 + kph;         // + ni*1024

  i32x4 acc[8][4];
#pragma unroll
  for (int i = 0; i < 8; ++i)
#pragma unroll
    for (int j = 0; j < 4; ++j)
#pragma unroll
      for (int q = 0; q < 4; ++q) acc[i][j][q] = 0;

  const int NT = K / 64;

  i32x4 Aa[8], Ba[4], Ab[8], Bb[4];

  i8* const q0 = &SM[0][0];
  i8* const q1 = &SM[1][0];
  i8* const q2 = &SM[2][0];

  // ---- prologue: stage S(0)->q0, S(1)->q1; retire S(0); read frags(0) ----
  STAGE12(q0, 0);
  STAGE12(q1, 64);
  VMCNT12;                      // S(0) complete; S(1) (12) in flight
  READ_FRAGS(q0, Aa, Ba);       // frags(0): 12 lgkm outstanding
  // steady-state invariants now hold: vm={S(1):12}, lgkm={frags(0):12}

  // unroll 6 = LCM(buffer period 3, frag-set period 2)
  for (int t = 0; t < NT; t += 6) {
    DO_TILE(t,     q0, q1, q2, Aa, Ba, Ab, Bb);
    DO_TILE(t + 1, q1, q2, q0, Ab, Bb, Aa, Ba);
    DO_TILE(t + 2, q2, q0, q1, Aa, Ba, Ab, Bb);
    DO_TILE(t + 3, q0, q1, q2, Ab, Bb, Aa, Ba);
    DO_TILE(t + 4, q1, q2, q0, Aa, Ba, Ab, Bb);
    DO_TILE(t + 5, q2, q0, q1, Ab, Bb, Aa, Ba);
  }

  // ---- epilogue: C = acc * alpha[col]/32 + bias[col] (nontemporal) ----
  const int r0 = tm * 128 + ((lane >> 4) << 2);
  const int c0 = tn * 64 + l15;
#pragma unroll
  for (int an = 0; an < 4; ++an) {
    const int col = c0 + an * 16;
    const float al = alpha[col] * INV_XSCALE;
    const float bi = bias[col];
#pragma unroll
    for (int am = 0; am < 8; ++am) {
#pragma unroll
      for (int j = 0; j < 4; ++j) {
        __builtin_nontemporal_store((float)acc[am][an][j] * al + bi,
                                    &C[(size_t)(r0 + am * 16 + j) * N + col]);
      }
    }
  }
}

// ---------------- fallback (insurance: ws too small / bad dims) ----------------

__global__ __launch_bounds__(256) void naive_kernel(
    const float* __restrict__ x, const float* __restrict__ w,
    const float* __restrict__ alpha, const float* __restrict__ bias,
    float* __restrict__ out, int M, int N, int K) {
  long idx = (long)blockIdx.x * blockDim.x + threadIdx.x;
  const long total = (long)M * N;
  const long stride = (long)gridDim.x * blockDim.x;
  for (; idx < total; idx += stride) {
    const int m = (int)(idx / N);
    const int n = (int)(idx % N);
    const float* xr = x + (size_t)m * K;
    const float* wr = w + (size_t)n * K;
    float s = 0.0f;
    for (int k = 0; k < K; ++k) {
      const float wv = wr[k];
      const float sg = (wv > 0.0f) ? 1.0f : ((wv < 0.0f) ? -1.0f : 0.0f);
      s += xr[k] * sg;
    }
    out[idx] = s * alpha[n] + bias[n];
  }
}

// ---------------- launcher ----------------

extern "C" void kernel_launch(void* const* d_in, const int* in_sizes, int n_in,
                              void* d_out, int out_size, void* d_ws, size_t ws_size,
                              hipStream_t stream) {
  const float* x = (const float*)d_in[0];
  const float* w = (const float*)d_in[1];
  const float* alpha = (const float*)d_in[2];
  const float* bias = (const float*)d_in[3];
  float* out = (float*)d_out;

  const int OUT = in_sizes[3];                // bias length
  const int IN = in_sizes[1] / OUT;           // weight is [OUT][IN]
  const int M = in_sizes[0] / IN;             // x is [B][IN]
  const int N = OUT, K = IN;

  const size_t xbytes = (size_t)M * K;        // i8
  const size_t wbytes = (size_t)N * K;        // i8
  // prologue needs NT = K/64 >= 2.
  const bool ok = (ws_size >= xbytes + wbytes) &&
                  (M % 128 == 0) && (N % 64 == 0) && (K % 64 == 0) &&
                  (K >= 128);

  if (!ok) {
    naive_kernel<<<2048, 256, 0, stream>>>(x, w, alpha, bias, out, M, N, K);
    return;
  }

  i8* xb = (i8*)d_ws;
  i8* wb = xb + xbytes;

  cvt_x_kernel<<<2048, 256, 0, stream>>>(x, (i32x4*)xb, (int)((size_t)M * K / 16));
  cvt_w_kernel<<<2048, 256, 0, stream>>>(w, (i32x4*)wb, (int)((size_t)N * K / 16));

  const int grid = (M / 128) * (N / 64);
  bingemm1w_kernel<<<grid, 64, 0, stream>>>(xb, wb, alpha, bias, out, M, N, K);
}

// Round 13
// 217.190 us; speedup vs baseline: 1.1275x; 1.1275x over previous
//
#include <hip/hip_runtime.h>
#include <stdint.h>

typedef signed char i8;
typedef __attribute__((ext_vector_type(4))) float f32x4;
typedef __attribute__((ext_vector_type(4))) int i32x4;

#define XSCALE 32.0f
#define INV_XSCALE (1.0f / 32.0f)

// ---------------- conversion kernels ----------------

__device__ __forceinline__ int q8(float f) {
  float s = rintf(f * XSCALE);
  s = fminf(fmaxf(s, -127.0f), 127.0f);
  return ((int)s) & 0xff;
}

// x fp32 -> i8 (scale 32), 16 elems/thread
__global__ __launch_bounds__(256) void cvt_x_kernel(const float* __restrict__ x,
                                                    i32x4* __restrict__ o, int n16) {
  int i = blockIdx.x * blockDim.x + threadIdx.x;
  int stride = gridDim.x * blockDim.x;
  for (; i < n16; i += stride) {
    const f32x4* p = (const f32x4*)x + (size_t)i * 4;
    f32x4 v0 = p[0], v1 = p[1], v2 = p[2], v3 = p[3];
    i32x4 r;
    r[0] = q8(v0[0]) | (q8(v0[1]) << 8) | (q8(v0[2]) << 16) | (q8(v0[3]) << 24);
    r[1] = q8(v1[0]) | (q8(v1[1]) << 8) | (q8(v1[2]) << 16) | (q8(v1[3]) << 24);
    r[2] = q8(v2[0]) | (q8(v2[1]) << 8) | (q8(v2[2]) << 16) | (q8(v2[3]) << 24);
    r[3] = q8(v3[0]) | (q8(v3[1]) << 8) | (q8(v3[2]) << 16) | (q8(v3[3]) << 24);
    o[i] = r;
  }
}

__device__ __forceinline__ int sg8(float f) {
  return (f > 0.0f ? 1 : (f < 0.0f ? -1 : 0)) & 0xff;
}

// w fp32 -> sign i8 (+1/-1/0), 16 elems/thread
__global__ __launch_bounds__(256) void cvt_w_kernel(const float* __restrict__ w,
                                                    i32x4* __restrict__ o, int n16) {
  int i = blockIdx.x * blockDim.x + threadIdx.x;
  int stride = gridDim.x * blockDim.x;
  for (; i < n16; i += stride) {
    const f32x4* p = (const f32x4*)w + (size_t)i * 4;
    f32x4 v0 = p[0], v1 = p[1], v2 = p[2], v3 = p[3];
    i32x4 r;
    r[0] = sg8(v0[0]) | (sg8(v0[1]) << 8) | (sg8(v0[2]) << 16) | (sg8(v0[3]) << 24);
    r[1] = sg8(v1[0]) | (sg8(v1[1]) << 8) | (sg8(v1[2]) << 16) | (sg8(v1[3]) << 24);
    r[2] = sg8(v2[0]) | (sg8(v2[1]) << 8) | (sg8(v2[2]) << 16) | (sg8(v2[3]) << 24);
    r[3] = sg8(v3[0]) | (sg8(v3[1]) << 8) | (sg8(v3[2]) << 16) | (sg8(v3[3]) << 24);
    o[i] = r;
  }
}

// ---------------- 128x128 i8 GEMM, 4 independent 4-wave blocks/CU ---------
// r26: maximize independent-barrier-group mixing per SIMD -- the ONLY
// mechanism that moved time in 15 variants:
//   1 group/SIMD (any schedule/occupancy/shape/depth): 160-168us
//   2 groups/SIMD (r20): 154us
//   1 wave/SIMD total (r25): 248us (nothing to mix with + traffic amp)
// Here: 4 co-resident 4-wave blocks (128KB LDS), so each SIMD hosts 4
// waves from 4 DIFFERENT free-running barrier groups. Block 128x128,
// wave tile 64x64 (r20's proven register shape: VGPR ~60 + acc 64 ~ 124
// combined -> 4 waves/SIMD fits the 512 budget; __launch_bounds__(256,4)
// pins it). LDS double-buffer 2 x (A 8KB + B 8KB) = 32KB/block. Per-tile
// schedule = r20's serial skeleton; dbuf forces a per-tile VMCNT0 drain,
// which is exactly what the other 3 groups hide (while this block drains,
// 3 unrelated blocks are mid-MFMA on the same SIMD).
// Port accounting per CU-round: MFMA 1306 cyc, LDS 1536 read + ~500
// write ~ 2036 -> floor ~108us at perfect mixing.
// Safety (dbuf): tile t stages S(t+1) into buf[(t+1)&1], which was last
// read at tile t-1 (ds_reads retired at t-1's WAITL0, before t-1's BAR);
// the stage issues after that BAR. Visibility: each wave drains its own
// S(t+1) at VMCNT0 before BAR; BAR publishes for tile t+1's reads.

__device__ __forceinline__ void load_lds16(const void* g, void* l) {
  __builtin_amdgcn_global_load_lds(
      (const __attribute__((address_space(1))) void*)g,
      (__attribute__((address_space(3))) void*)l,
      16, 0, 0);
}

// stage one 4KB unit (64 rows x 64 cols i8) with 4 waves x 1KB; u=0,1.
__device__ __forceinline__ void stage_u4(const i8* __restrict__ Gp, int K, int k0,
                                         i8* __restrict__ Tlds, int u, int wave,
                                         int lane) {
  const int base = u * 4096 + wave * 1024;        // physical byte base (wave-uniform)
  const int PA = base + lane * 16;                // this lane's physical bytes
  const int L = PA ^ (((PA >> 7) & 3) << 4);      // logical bytes (involution)
  const int r = L >> 6;                           // tile row (64 i8 per row)
  const int c = L & 63;                           // tile col (16-aligned)
  load_lds16(Gp + (size_t)r * K + k0 + c, Tlds + base);
}

#define BAR __builtin_amdgcn_s_barrier()
#define SGB __builtin_amdgcn_sched_barrier(0)
#define WAITL0 asm volatile("s_waitcnt lgkmcnt(0)" ::: "memory")
#define VMCNT0 asm volatile("s_waitcnt vmcnt(0)" ::: "memory")

#define MFMA16                                                                  \
  __builtin_amdgcn_s_setprio(1);                                                \
  _Pragma("unroll") for (int mi = 0; mi < 4; ++mi)                              \
  _Pragma("unroll") for (int ni = 0; ni < 4; ++ni)                              \
    acc[mi][ni] = __builtin_amdgcn_mfma_i32_16x16x64_i8(                        \
        Af[mi], Bf[ni], acc[mi][ni], 0, 0, 0);                                  \
  __builtin_amdgcn_s_setprio(0);

// Buffer layout (16KB): A [128][64] at +0, B [128][64] at +8192.
// CUR = buf[t&1] (read tile t), NXT = buf[(t+1)&1] (stage tile t+1).
#define DO_TILE(t, CUR, NXT)                                                    \
  if ((t) < NT) {                                                               \
    if ((t) + 1 < NT) {                                                         \
      const int k1 = ((t) + 1) * 64;                                            \
      stage_u4(GA, K, k1, (NXT), 0, wave, lane);                                \
      stage_u4(GA, K, k1, (NXT), 1, wave, lane);                                \
      stage_u4(GB, K, k1, (NXT) + 8192, 0, wave, lane);                         \
      stage_u4(GB, K, k1, (NXT) + 8192, 1, wave, lane);                         \
    }                                                                           \
    _Pragma("unroll") for (int mi = 0; mi < 4; ++mi)                            \
      Af[mi] = *(const i32x4*)((CUR) + abase + mi * 1024);                      \
    _Pragma("unroll") for (int ni = 0; ni < 4; ++ni)                            \
      Bf[ni] = *(const i32x4*)((CUR) + 8192 + bbase + ni * 1024);               \
    WAITL0; SGB;                                                                \
    MFMA16;                                                                     \
    SGB;                                                                        \
    if ((t) + 1 < NT) { VMCNT0; }                                               \
    BAR;                                                                        \
  }

__global__ __launch_bounds__(256, 4) void bingemm4g_kernel(
    const i8* __restrict__ A,      // [M][K] i8 (x * 32)
    const i8* __restrict__ B,      // [N][K] i8 sign
    const float* __restrict__ alpha,
    const float* __restrict__ bias,
    float* __restrict__ C,         // [M][N] fp32
    int M, int N, int K) {
  __shared__ i8 SM[2][16384];      // dbuf x (A 8KB + B 8KB) = 32 KB

  const int tid = threadIdx.x;
  const int lane = tid & 63;
  const int wave = tid >> 6;  // 0..3
  const int wm = wave >> 1;   // 0..1 (64-row slab)
  const int wn = wave & 1;    // 0..1 (64-col slab)
  const int l15 = lane & 15;

  // XCD-aware swizzle (grid divisible by 8 -> simple bijection)
  const int nwg = gridDim.x;
  const int wg = blockIdx.x;
  const int wgid = ((nwg & 7) == 0) ? ((wg & 7) * (nwg >> 3) + (wg >> 3)) : wg;

  const int nbn = N / 128;
  const int tm = wgid / nbn;
  const int tn = wgid % nbn;

  const i8* GA = A + (size_t)tm * 128 * K;
  const i8* GB = B + (size_t)tn * 128 * K;

  // swizzled ds_read byte offsets (row stride 64B, granule 16B):
  // phys k-part = (kq ^ ((row>>1)&3))<<4, (row>>1)&3 == (l15>>1)&3
  const int kq = lane >> 4;                 // 0..3
  const int kph = ((kq ^ ((l15 >> 1) & 3)) << 4);
  const int abase = (wm * 64 + l15) * 64 + kph;    // + mi*1024 (16 rows)
  const int bbase = (wn * 64 + l15) * 64 + kph;    // + ni*1024

  i32x4 acc[4][4];
#pragma unroll
  for (int i = 0; i < 4; ++i)
#pragma unroll
    for (int j = 0; j < 4; ++j)
#pragma unroll
      for (int q = 0; q < 4; ++q) acc[i][j][q] = 0;

  const int NT = K / 64;

  i32x4 Af[4], Bf[4];

  i8* const b0 = &SM[0][0];
  i8* const b1 = &SM[1][0];

  // ---- prologue: stage S(0)->b0; drain; publish ----
  stage_u4(GA, K, 0, b0, 0, wave, lane);
  stage_u4(GA, K, 0, b0, 1, wave, lane);
  stage_u4(GB, K, 0, b0 + 8192, 0, wave, lane);
  stage_u4(GB, K, 0, b0 + 8192, 1, wave, lane);
  VMCNT0;
  BAR;

  for (int t = 0; t < NT; t += 2) {
    DO_TILE(t,     b0, b1);
    DO_TILE(t + 1, b1, b0);
  }

  // ---- epilogue: C = acc * alpha[col]/32 + bias[col] (nontemporal) ----
  const int r0 = tm * 128 + wm * 64 + ((lane >> 4) << 2);
  const int c0 = tn * 128 + wn * 64 + l15;
#pragma unroll
  for (int an = 0; an < 4; ++an) {
    const int col = c0 + an * 16;
    const float al = alpha[col] * INV_XSCALE;
    const float bi = bias[col];
#pragma unroll
    for (int am = 0; am < 4; ++am) {
#pragma unroll
      for (int j = 0; j < 4; ++j) {
        __builtin_nontemporal_store((float)acc[am][an][j] * al + bi,
                                    &C[(size_t)(r0 + am * 16 + j) * N + col]);
      }
    }
  }
}

// ---------------- fallback (insurance: ws too small / bad dims) ----------------

__global__ __launch_bounds__(256) void naive_kernel(
    const float* __restrict__ x, const float* __restrict__ w,
    const float* __restrict__ alpha, const float* __restrict__ bias,
    float* __restrict__ out, int M, int N, int K) {
  long idx = (long)blockIdx.x * blockDim.x + threadIdx.x;
  const long total = (long)M * N;
  const long stride = (long)gridDim.x * blockDim.x;
  for (; idx < total; idx += stride) {
    const int m = (int)(idx / N);
    const int n = (int)(idx % N);
    const float* xr = x + (size_t)m * K;
    const float* wr = w + (size_t)n * K;
    float s = 0.0f;
    for (int k = 0; k < K; ++k) {
      const float wv = wr[k];
      const float sg = (wv > 0.0f) ? 1.0f : ((wv < 0.0f) ? -1.0f : 0.0f);
      s += xr[k] * sg;
    }
    out[idx] = s * alpha[n] + bias[n];
  }
}

// ---------------- launcher ----------------

extern "C" void kernel_launch(void* const* d_in, const int* in_sizes, int n_in,
                              void* d_out, int out_size, void* d_ws, size_t ws_size,
                              hipStream_t stream) {
  const float* x = (const float*)d_in[0];
  const float* w = (const float*)d_in[1];
  const float* alpha = (const float*)d_in[2];
  const float* bias = (const float*)d_in[3];
  float* out = (float*)d_out;

  const int OUT = in_sizes[3];                // bias length
  const int IN = in_sizes[1] / OUT;           // weight is [OUT][IN]
  const int M = in_sizes[0] / IN;             // x is [B][IN]
  const int N = OUT, K = IN;

  const size_t xbytes = (size_t)M * K;        // i8
  const size_t wbytes = (size_t)N * K;        // i8
  const bool ok = (ws_size >= xbytes + wbytes) &&
                  (M % 128 == 0) && (N % 128 == 0) && (K % 64 == 0) &&
                  (K >= 128);

  if (!ok) {
    naive_kernel<<<2048, 256, 0, stream>>>(x, w, alpha, bias, out, M, N, K);
    return;
  }

  i8* xb = (i8*)d_ws;
  i8* wb = xb + xbytes;

  cvt_x_kernel<<<2048, 256, 0, stream>>>(x, (i32x4*)xb, (int)((size_t)M * K / 16));
  cvt_w_kernel<<<2048, 256, 0, stream>>>(w, (i32x4*)wb, (int)((size_t)N * K / 16));

  const int grid = (M / 128) * (N / 128);
  bingemm4g_kernel<<<grid, 256, 0, stream>>>(xb, wb, alpha, bias, out, M, N, K);
}